// Round 4
// baseline (187.929 us; speedup 1.0000x reference)
//
#include <hip/hip_runtime.h>
#include <math.h>

#define P_N 64
#define B_N 32
#define A_N 40
#define D_N 128

// ---------------- scale: v1 = dp*exp(gamma), v2 = x*exp(gamma) ----------------
__global__ __launch_bounds__(256) void scale_kernel(
    const float* __restrict__ x, const float* __restrict__ dp,
    const float* __restrict__ gamma, float* __restrict__ v1, float* __restrict__ v2) {
  int t = blockIdx.x * 256 + threadIdx.x;          // float4 index
  const int n1 = P_N * A_N * D_N / 4;              // 81920
  const int n2 = B_N * A_N * D_N / 4;              // 40960
  if (t >= n1 + n2) return;
  int d4 = t & 31;                                  // 32 float4 per 128-dim row
  float4 g = ((const float4*)gamma)[d4];
  float gx = expf(g.x), gy = expf(g.y), gz = expf(g.z), gw = expf(g.w);
  if (t < n1) {
    float4 a = ((const float4*)dp)[t];
    ((float4*)v1)[t] = make_float4(a.x*gx, a.y*gy, a.z*gz, a.w*gw);
  } else {
    int s = t - n1;
    float4 a = ((const float4*)x)[s];
    ((float4*)v2)[s] = make_float4(a.x*gx, a.y*gy, a.z*gz, a.w*gw);
  }
}

// ---- helpers: uniform-lane broadcast (VALU latency, not ds_bpermute) ----
__device__ __forceinline__ int readlane_i(int v, int l) {
  return __builtin_amdgcn_readlane(v, l);
}
__device__ __forceinline__ float readlane_f(float v, int l) {
  return __int_as_float(__builtin_amdgcn_readlane(__float_as_int(v), l));
}
// order-preserving float->uint map (handles tiny negatives from rounding)
__device__ __forceinline__ unsigned ordf(float f) {
  unsigned b = __float_as_uint(f);
  return (b & 0x80000000u) ? ~b : (b | 0x80000000u);
}
// full-wave min via DPP (gfx9 canonical sequence), result broadcast from lane 63
__device__ __forceinline__ unsigned wave_min_u32(unsigned x) {
  unsigned t;
  t = (unsigned)__builtin_amdgcn_update_dpp((int)0xFFFFFFFFu, (int)x, 0x111, 0xF, 0xF, false); // row_shr:1
  x = t < x ? t : x;
  t = (unsigned)__builtin_amdgcn_update_dpp((int)0xFFFFFFFFu, (int)x, 0x112, 0xF, 0xF, false); // row_shr:2
  x = t < x ? t : x;
  t = (unsigned)__builtin_amdgcn_update_dpp((int)0xFFFFFFFFu, (int)x, 0x114, 0xF, 0xF, false); // row_shr:4
  x = t < x ? t : x;
  t = (unsigned)__builtin_amdgcn_update_dpp((int)0xFFFFFFFFu, (int)x, 0x118, 0xF, 0xF, false); // row_shr:8
  x = t < x ? t : x;
  t = (unsigned)__builtin_amdgcn_update_dpp((int)0xFFFFFFFFu, (int)x, 0x142, 0xA, 0xF, false); // row_bcast:15
  x = t < x ? t : x;
  t = (unsigned)__builtin_amdgcn_update_dpp((int)0xFFFFFFFFu, (int)x, 0x143, 0xC, 0xF, false); // row_bcast:31
  x = t < x ? t : x;
  return (unsigned)__builtin_amdgcn_readlane((int)x, 63);
}

// ---------------- Hungarian (JV) — one wave per (p,b) cost matrix ----------------
// Lane j = column j (0 = dummy, 1..40 real). Lane r also holds row-potential u[r].
// Init: column reduction + col-greedy, then augmenting row reduction
// (u[i] = min_j(C[i][j]-v[j]), assign if argmin col free), then exact
// shortest-augmenting-path for remaining free rows (still exact optimum).
__global__ __launch_bounds__(64) void hungarian_pair(
    const float* __restrict__ V1, const float* __restrict__ V2,
    float* __restrict__ out) {
  __shared__ float Cs[A_N * A_N];
  const int bid  = blockIdx.x;
  const int lane = threadIdx.x;
  const float* __restrict__ Abase = V1 + (bid >> 5) * (A_N * D_N);
  const float* __restrict__ Bbase = V2 + (bid & 31) * (A_N * D_N);

  // ---- build C[i][j] = |A_i - B_j|^2 ; lane j owns column j ----
  if (lane < A_N) {
    const float* bp = Bbase + lane * D_N;
    for (int c = 0; c < 4; ++c) {                   // 4 chunks of 32 dims
      float4 bb[8];
      #pragma unroll
      for (int k = 0; k < 8; ++k) bb[k] = ((const float4*)(bp + c * 32))[k];
      for (int i = 0; i < A_N; ++i) {
        const float4* ap = (const float4*)(Abase + i * D_N + c * 32); // uniform addr -> broadcast
        float s = 0.f;
        #pragma unroll
        for (int k = 0; k < 8; ++k) {
          float4 a = ap[k];
          float dx = a.x - bb[k].x; s = fmaf(dx, dx, s);
          float dy = a.y - bb[k].y; s = fmaf(dy, dy, s);
          float dz = a.z - bb[k].z; s = fmaf(dz, dz, s);
          float dw = a.w - bb[k].w; s = fmaf(dw, dw, s);
        }
        if (c == 0) Cs[i * A_N + lane] = s;
        else        Cs[i * A_N + lane] += s;
      }
    }
  }
  __syncthreads();

  const int cix = (lane >= 1 && lane <= A_N) ? (lane - 1) : 0;  // safe column index
  const bool realcol = (lane >= 1 && lane <= A_N);

  // ---- column reduction: v[j] = min_i C[i][j], remember argmin row ----
  float vinit = 0.f;
  int   amin  = 0;                       // 1-based argmin row for this column
  if (realcol) {
    float mn = INFINITY; int mi = 0;
    for (int i = 0; i < A_N; ++i) {
      float c = Cs[i * A_N + cix];
      if (c < mn) { mn = c; mi = i; }
    }
    vinit = mn; amin = mi + 1;
  }

  // ---- greedy assignment on tight edges (u=0, v=colmin) ----
  unsigned long long rmask = 0ull;       // bit r = row r matched (identical on all lanes)
  int p = 0, way = 0;                    // p: row matched to this column (0 = free)
  for (int j = 1; j <= A_N; ++j) {
    int am = readlane_i(amin, j);
    if (!((rmask >> am) & 1ull)) {
      rmask |= 1ull << am;
      if (lane == j) p = am;
    }
  }

  float u = 0.f, v = vinit;    // u: row potential (lane=row 1..40); v: col potential (lane=col)

  // ---- augmenting row reduction: u[i] = min_j (C[i][j]-v[j]); assign if col free ----
  for (int i = 1; i <= A_N; ++i) {
    if ((rmask >> i) & 1ull) continue;
    float r = realcol ? (Cs[(i - 1) * A_N + cix] - v) : INFINITY;
    unsigned key = (ordf(r) & 0xFFFFFFC0u) | (unsigned)lane;
    unsigned kmin = wave_min_u32(key);
    int   jm   = (int)(kmin & 63u);
    float rmin = readlane_f(r, jm);
    if (lane == i) u = rmin;             // tight admissible row potential
    int pj = readlane_i(p, jm);
    if (pj == 0) {                        // argmin column free -> assign tight edge
      if (lane == jm) p = i;
      rmask |= 1ull << i;
    }
  }

  // ---- shortest augmenting path for remaining free rows ----
  for (int i = 1; i <= A_N; ++i) {
    if ((rmask >> i) & 1ull) continue;    // matched — skip (wave-uniform)
    if (lane == 0) p = i;                 // p[0] = i
    float minv   = INFINITY;
    bool  used   = (lane > A_N);          // lanes 41..63 permanently masked
    bool  rowuse = false;                 // this lane's row is in the alternating tree
    int   j0 = 0;
    int   i0 = i;                         // = p[j0] for j0=0
    for (int guard = 0; guard < 42; ++guard) {
      if (lane == j0) used = true;
      if (lane == i0) rowuse = true;
      float ui0 = readlane_f(u, i0);
      float cur = Cs[(i0 - 1) * A_N + cix] - ui0 - v;
      if (!used && cur < minv) { minv = cur; way = j0; }
      // argmin over unused columns via packed-key DPP min (lowest lane on ~ties)
      float mval = used ? INFINITY : minv;
      unsigned key = (ordf(mval) & 0xFFFFFFC0u) | (unsigned)lane;
      unsigned kmin = wave_min_u32(key);
      int   j1    = (int)(kmin & 63u);
      float delta = readlane_f(mval, j1);   // exact masked minv at winner
      if (rowuse) u += delta;               // u[p[j]] += delta for used j
      if (used)   v -= delta;
      else        minv -= delta;
      j0 = j1;
      i0 = readlane_i(p, j0);
      if (i0 == 0) break;                   // reached a free column
    }
    // augment along way[] back to the dummy column
    while (j0 != 0) {
      int jn = readlane_i(way, j0);
      int pn = readlane_i(p, jn);
      if (lane == j0) p = pn;
      j0 = jn;
    }
  }

  // ---- matched-kernel value: sum_j exp(-C[p[j]-1][j-1]) / 40 ----
  float e = 0.f;
  if (realcol) e = expf(-Cs[(p - 1) * A_N + (lane - 1)]);
  #pragma unroll
  for (int off = 32; off; off >>= 1) e += __shfl_xor(e, off);
  if (lane == 0) out[bid] = e / 40.0f;
}

// ---------------- mean + triangular solve + var (kxx == 1.0, see note) ----------------
// Self-distance diagonal is |v-v|^2 = 0 (ref: abs(-2*dot+s+s) ~ 1e-6), Hungarian on it
// is identity, so kxx = sum(exp(-~0))/40 = 1 - O(1e-6). Hard-code 1.0f.
__global__ __launch_bounds__(64) void final_kernel(
    const float* __restrict__ Kx, const float* __restrict__ L,
    const float* __restrict__ alpha, float* __restrict__ out) {
  __shared__ float vl[P_N * B_N];
  int b = threadIdx.x;
  if (b >= B_N) return;
  float mean = 0.f;
  for (int p = 0; p < P_N; ++p) mean = fmaf(Kx[p * B_N + b], alpha[p], mean);
  out[b] = mean;
  // forward substitution: L * v = Kx[:, b]   (== inv(L) @ Kx)
  float sumv2 = 0.f;
  for (int i = 0; i < P_N; ++i) {
    float s = Kx[i * B_N + b];
    for (int j = 0; j < i; ++j) s = fmaf(-L[i * P_N + j], vl[j * B_N + b], s);
    float vi = s / L[i * P_N + i];
    vl[i * B_N + b] = vi;
    sumv2 = fmaf(vi, vi, sumv2);
  }
  out[B_N + b] = 1.0f - sumv2;
}

extern "C" void kernel_launch(void* const* d_in, const int* in_sizes, int n_in,
                              void* d_out, int out_size, void* d_ws, size_t ws_size,
                              hipStream_t stream) {
  const float* x     = (const float*)d_in[0];   // [32,40,128]
  const float* dp    = (const float*)d_in[1];   // [64,40,128]
  const float* gamma = (const float*)d_in[2];   // [1,128]
  const float* L     = (const float*)d_in[3];   // [64,64]
  const float* alpha = (const float*)d_in[4];   // [64]
  float* out = (float*)d_out;                   // mean[32] ++ var[32]

  float* v1 = (float*)d_ws;                     // 327680 f32
  float* v2 = v1 + P_N * A_N * D_N;             // 163840 f32
  float* Kx = v2 + B_N * A_N * D_N;             // 2048 f32  (total ~1.93 MB)

  scale_kernel<<<480, 256, 0, stream>>>(x, dp, gamma, v1, v2);
  hungarian_pair<<<P_N * B_N, 64, 0, stream>>>(v1, v2, Kx);
  final_kernel<<<1, 64, 0, stream>>>(Kx, L, alpha, out);
}

// Round 6
// 149.676 us; speedup vs baseline: 1.2556x; 1.2556x over previous
//
#include <hip/hip_runtime.h>
#include <math.h>

#define P_N 64
#define B_N 32
#define A_N 40
#define D_N 128

// ---- helpers: uniform-lane broadcast (VALU latency, not ds_bpermute) ----
__device__ __forceinline__ int readlane_i(int v, int l) {
  return __builtin_amdgcn_readlane(v, l);
}
__device__ __forceinline__ float readlane_f(float v, int l) {
  return __int_as_float(__builtin_amdgcn_readlane(__float_as_int(v), l));
}
// order-preserving float->uint map (handles tiny negatives from rounding)
__device__ __forceinline__ unsigned ordf(float f) {
  unsigned b = __float_as_uint(f);
  return (b & 0x80000000u) ? ~b : (b | 0x80000000u);
}
// full-wave min via DPP (gfx9 canonical sequence), result broadcast from lane 63
__device__ __forceinline__ unsigned wave_min_u32(unsigned x) {
  unsigned t;
  t = (unsigned)__builtin_amdgcn_update_dpp((int)0xFFFFFFFFu, (int)x, 0x111, 0xF, 0xF, false); // row_shr:1
  x = t < x ? t : x;
  t = (unsigned)__builtin_amdgcn_update_dpp((int)0xFFFFFFFFu, (int)x, 0x112, 0xF, 0xF, false); // row_shr:2
  x = t < x ? t : x;
  t = (unsigned)__builtin_amdgcn_update_dpp((int)0xFFFFFFFFu, (int)x, 0x114, 0xF, 0xF, false); // row_shr:4
  x = t < x ? t : x;
  t = (unsigned)__builtin_amdgcn_update_dpp((int)0xFFFFFFFFu, (int)x, 0x118, 0xF, 0xF, false); // row_shr:8
  x = t < x ? t : x;
  t = (unsigned)__builtin_amdgcn_update_dpp((int)0xFFFFFFFFu, (int)x, 0x142, 0xA, 0xF, false); // row_bcast:15
  x = t < x ? t : x;
  t = (unsigned)__builtin_amdgcn_update_dpp((int)0xFFFFFFFFu, (int)x, 0x143, 0xC, 0xF, false); // row_bcast:31
  x = t < x ? t : x;
  return (unsigned)__builtin_amdgcn_readlane((int)x, 63);
}

// ---------------- Hungarian (JV) — one wave per (p,b) cost matrix ----------------
// Lane j = column j (0 = dummy, 1..40 real). Lane r also holds row-potential u[r].
// Build fuses the gamma scaling (t = fma(a, g, -b*g)). Init = column reduction +
// col-greedy on tight edges. Search = deferred-potential Dijkstra: mhat_j =
// min_i (A_j(i) + Dsum_entry); key packs (val20|p6|lane6) so i0 comes out of the
// DPP result; u/v updates batched at end of each search.
// R5 bug fixed: p[0] = f must be set at search start (augmentation terminates by
// reading p[0]); without it the first path column got row 0 -> OOB LDS read.
__global__ __launch_bounds__(64) void hungarian_pair(
    const float* __restrict__ DP, const float* __restrict__ X,
    const float* __restrict__ G, float* __restrict__ out) {
  __shared__ float Cs[A_N * A_N];
  const int bid  = blockIdx.x;
  const int lane = threadIdx.x;
  const float* __restrict__ Abase = DP + (bid >> 5) * (A_N * D_N);
  const float* __restrict__ Bbase = X  + (bid & 31) * (A_N * D_N);

  // ---- build C[i][j] = |g*(A_i - B_j)|^2 ; lane j owns column j ----
  if (lane < A_N) {
    const float* bp = Bbase + lane * D_N;
    for (int c = 0; c < 4; ++c) {                   // 4 chunks of 32 dims
      float4 gg[8], bb[8];
      #pragma unroll
      for (int k = 0; k < 8; ++k) {
        float4 gr = ((const float4*)(G + c * 32))[k];        // uniform
        gg[k] = make_float4(expf(gr.x), expf(gr.y), expf(gr.z), expf(gr.w));
        float4 br = ((const float4*)(bp + c * 32))[k];
        bb[k] = make_float4(br.x * gg[k].x, br.y * gg[k].y,
                            br.z * gg[k].z, br.w * gg[k].w);
      }
      for (int i = 0; i < A_N; ++i) {
        const float4* ap = (const float4*)(Abase + i * D_N + c * 32); // uniform -> broadcast
        float s = 0.f;
        #pragma unroll
        for (int k = 0; k < 8; ++k) {
          float4 a = ap[k];
          float dx = fmaf(a.x, gg[k].x, -bb[k].x); s = fmaf(dx, dx, s);
          float dy = fmaf(a.y, gg[k].y, -bb[k].y); s = fmaf(dy, dy, s);
          float dz = fmaf(a.z, gg[k].z, -bb[k].z); s = fmaf(dz, dz, s);
          float dw = fmaf(a.w, gg[k].w, -bb[k].w); s = fmaf(dw, dw, s);
        }
        if (c == 0) Cs[i * A_N + lane] = s;
        else        Cs[i * A_N + lane] += s;
      }
    }
  }
  __syncthreads();

  const int  cix     = (lane >= 1 && lane <= A_N) ? (lane - 1) : 0;
  const bool realcol = (lane >= 1 && lane <= A_N);

  // ---- column reduction: v[j] = min_i C[i][j], remember argmin row ----
  float vpot = 0.f;
  int   amin = 0;                        // 1-based argmin row for this column
  if (realcol) {
    float mn = INFINITY; int mi = 0;
    for (int i = 0; i < A_N; ++i) {
      float c = Cs[i * A_N + cix];
      if (c < mn) { mn = c; mi = i; }
    }
    vpot = mn; amin = mi + 1;
  }

  // ---- greedy assignment on tight edges (u=0, v=colmin) ----
  unsigned long long rmask = 0ull;       // bit r = row r matched (uniform across lanes)
  int p = 0, way = 0;                    // p: row matched to this column (0 = free)
  for (int j = 1; j <= A_N; ++j) {
    int am = readlane_i(amin, j);
    if (!((rmask >> am) & 1ull)) {
      rmask |= 1ull << am;
      if (lane == j) p = am;
    }
  }

  float u = 0.f;                         // row potential (lane = row 1..40)

  // ---- shortest augmenting path for remaining free rows (deferred potentials) ----
  for (int f = 1; f <= A_N; ++f) {
    if ((rmask >> f) & 1ull) continue;   // matched — skip (wave-uniform)
    if (lane == 0) p = f;                // p[0] = f  (augmentation reads this!)
    float mhat = INFINITY;               // min_i (A_j(i) + Dsum_entry(i))
    float dsum = 0.f;                    // accumulated delta (current Dijkstra radius)
    float dent = 0.f, rent = 0.f;        // Dsum when this col became used / row entered
    bool  used   = (lane == 0) || (lane > A_N);
    bool  intree = (lane == f);
    int   j0 = 0, i0 = f;
    for (int guard = 0; guard < 42; ++guard) {
      float Craw = Cs[(i0 - 1) * A_N + cix];        // ds_read issues first
      float uc   = readlane_f(u, i0);               // overlaps LDS latency
      float cand = Craw - uc - vpot + dsum;         // A_j(i0) + Dsum_entry
      if (!used && cand < mhat) { mhat = cand; way = j0; }
      unsigned key = used ? 0xFFFFFFFFu
                   : ((ordf(mhat) & 0xFFFFF000u) | ((unsigned)p << 6) | (unsigned)lane);
      unsigned kmin = wave_min_u32(key);
      int j1 = (int)(kmin & 63u);
      int i1 = (int)((kmin >> 6) & 63u);            // p[j1] from the key — no readlane
      dsum = readlane_f(mhat, j1);                  // exact; overlaps next ds_read
      if (lane == j1) { used = true; dent = dsum; }
      j0 = j1;
      i0 = i1;
      if (i1 == 0) break;                           // free column reached
      if (lane == i1) { intree = true; rent = dsum; }
    }
    // batched potential updates: v[j] -= (Dfinal - Dent_j), u[i] += (Dfinal - Rent_i)
    if (used && realcol) vpot -= (dsum - dent);
    if (intree)          u    += (dsum - rent);
    // augment along way[] back to the dummy column
    while (j0 != 0) {
      int jn = readlane_i(way, j0);
      int pn = readlane_i(p, jn);
      if (lane == j0) p = pn;
      j0 = jn;
    }
  }

  // ---- matched-kernel value: sum_j exp(-C[p[j]-1][j-1]) / 40 ----
  float e = 0.f;
  if (realcol) e = expf(-Cs[(p - 1) * A_N + (lane - 1)]);
  #pragma unroll
  for (int off = 32; off; off >>= 1) e += __shfl_xor(e, off);
  if (lane == 0) out[bid] = e / 40.0f;
}

// ---------------- mean + triangular solve + var (kxx == 1.0, see note) ----------------
// Self-distance diagonal is |v-v|^2 = 0 (ref: abs(-2*dot+s+s) ~ 1e-6), Hungarian on it
// is identity, so kxx = sum(exp(-~0))/40 = 1 - O(1e-6). Hard-code 1.0f.
__global__ __launch_bounds__(64) void final_kernel(
    const float* __restrict__ Kx, const float* __restrict__ L,
    const float* __restrict__ alpha, float* __restrict__ out) {
  __shared__ float vl[P_N * B_N];
  int b = threadIdx.x;
  if (b >= B_N) return;
  float mean = 0.f;
  for (int p = 0; p < P_N; ++p) mean = fmaf(Kx[p * B_N + b], alpha[p], mean);
  out[b] = mean;
  // forward substitution: L * v = Kx[:, b]   (== inv(L) @ Kx)
  float sumv2 = 0.f;
  for (int i = 0; i < P_N; ++i) {
    float s = Kx[i * B_N + b];
    for (int j = 0; j < i; ++j) s = fmaf(-L[i * P_N + j], vl[j * B_N + b], s);
    float vi = s / L[i * P_N + i];
    vl[i * B_N + b] = vi;
    sumv2 = fmaf(vi, vi, sumv2);
  }
  out[B_N + b] = 1.0f - sumv2;
}

extern "C" void kernel_launch(void* const* d_in, const int* in_sizes, int n_in,
                              void* d_out, int out_size, void* d_ws, size_t ws_size,
                              hipStream_t stream) {
  const float* x     = (const float*)d_in[0];   // [32,40,128]
  const float* dp    = (const float*)d_in[1];   // [64,40,128]
  const float* gamma = (const float*)d_in[2];   // [1,128]
  const float* L     = (const float*)d_in[3];   // [64,64]
  const float* alpha = (const float*)d_in[4];   // [64]
  float* out = (float*)d_out;                   // mean[32] ++ var[32]

  float* Kx = (float*)d_ws;                     // 2048 f32

  hungarian_pair<<<P_N * B_N, 64, 0, stream>>>(dp, x, gamma, Kx);
  final_kernel<<<1, 64, 0, stream>>>(Kx, L, alpha, out);
}